// Round 8
// baseline (354.136 us; speedup 1.0000x reference)
//
#include <hip/hip_runtime.h>

typedef unsigned int u32;
typedef unsigned short u16;
typedef unsigned long long u64;

// Problem constants
#define NPTS 65536
#define PCLD 2048
#define KNN 20
#define HD 128
#define HD2 256
// activations at rest: 16 slices of 8 channels, ORDER-ENCODED u16
// layout: he[slice][row][8]  (16 B per row per slice)

typedef __attribute__((ext_vector_type(8))) short bf16x8;   // 8 bf16 (4 VGPRs)
typedef __attribute__((ext_vector_type(4))) float f32x4;    // C/D frag
typedef unsigned short us2 __attribute__((ext_vector_type(2)));

__device__ __forceinline__ u16 f2bf(float f) {
    u32 u = __float_as_uint(f);
    u32 r = (u + 0x7FFFu + ((u >> 16) & 1u)) >> 16;  // RNE
    return (u16)r;
}
// order-encode: bf16 bits -> monotone u16 (unsigned compare == float compare)
__device__ __forceinline__ u32 enc2(u32 b) {             // 2 packed values
    u32 s = (b >> 15) & 0x00010001u;
    return b ^ (s * 0x7FFFu) ^ 0x80008000u;
}
__device__ __forceinline__ u32 dec2(u32 e) {
    u32 s = ((~e) >> 15) & 0x00010001u;
    return e ^ (s * 0x7FFFu) ^ 0x80008000u;
}
__device__ __forceinline__ u32 max2(u32 a, u32 b) {      // per-u16 unsigned max
#if __has_builtin(__builtin_elementwise_max)
    us2 x, y; __builtin_memcpy(&x, &a, 4); __builtin_memcpy(&y, &b, 4);
    us2 r = __builtin_elementwise_max(x, y);
    u32 o; __builtin_memcpy(&o, &r, 4); return o;
#else
    u32 lo = ((a & 0xFFFFu) > (b & 0xFFFFu)) ? (a & 0xFFFFu) : (b & 0xFFFFu);
    u32 hi = ((a >> 16) > (b >> 16)) ? (a & 0xFFFF0000u) : (b & 0xFFFF0000u);
    return lo | hi;
#endif
}

// ---------------------------------------------------------------------------
// Weight prep: fp32 -> bf16 + transpose (unchanged).
// ---------------------------------------------------------------------------
__global__ __launch_bounds__(256) void prep_kernel(
    const float* __restrict__ W1_0, const float* __restrict__ W2_0,
    const float* __restrict__ W1_1, const float* __restrict__ W2_1,
    u16* __restrict__ W1_0T, u16* __restrict__ W2_0T,
    u16* __restrict__ W1_1T, u16* __restrict__ W2_1T) {
    int id = blockIdx.x * 256 + threadIdx.x;   // 4 * 32768 threads
    int m = id >> 15, e = id & 32767;
    if (m == 0)      { int n = e >> 7, k = e & 127; W1_0T[e] = f2bf(W1_0[k * 256 + n]); }
    else if (m == 1) { int n = e >> 8, k = e & 255; W2_0T[e] = f2bf(W2_0[k * 128 + n]); }
    else if (m == 2) { int n = e >> 7, k = e & 127; W1_1T[e] = f2bf(W1_1[k * 256 + n]); }
    else             { int n = e >> 8, k = e & 255; W2_1T[e] = f2bf(W2_1[k * 128 + n]); }
}

// ---------------------------------------------------------------------------
// kNN — EXACT R2 structure (empirical best: 155 us; DO NOT MODIFY).
// readlane broadcast beat uniform-LDS (202), uniform-VMEM (204), SMEM (1200).
// ---------------------------------------------------------------------------
__global__ __launch_bounds__(256) void knn_kernel(const float* __restrict__ x,
                                                  u16* __restrict__ nbr) {
    __shared__ float4 pts[PCLD];
    const int cloud = blockIdx.x >> 3;
    const int qi = ((blockIdx.x & 7) << 8) + threadIdx.x;   // local query idx
    const float* xc = x + (u64)cloud * PCLD * 3;
    for (int t = threadIdx.x; t < PCLD; t += 256) {
        float a = xc[3 * t], b = xc[3 * t + 1], c = xc[3 * t + 2];
        float sq = __fadd_rn(__fadd_rn(__fmul_rn(a, a), __fmul_rn(b, b)), __fmul_rn(c, c));
        pts[t] = make_float4(a, b, c, sq);
    }
    __syncthreads();
    const float4 q = pts[qi];
    const float qx = q.x, qy = q.y, qz = q.z, qs = q.w;
    const int lane = threadIdx.x & 63;
    u64 list[KNN];
#pragma unroll
    for (int k = 0; k < KNN; ++k) list[k] = 0xFF800000FFFFFFFFull;  // enc(+inf)
    float thr = __builtin_inff();

    for (int base = 0; base < PCLD; base += 64) {
        float4 cp = pts[base + lane];   // 1 ds_read_b128 per 64 candidates
        u64 mask = 0;
#pragma unroll
        for (int c = 0; c < 64; ++c) {
            float cx = __uint_as_float(__builtin_amdgcn_readlane(__float_as_uint(cp.x), c));
            float cy = __uint_as_float(__builtin_amdgcn_readlane(__float_as_uint(cp.y), c));
            float cz = __uint_as_float(__builtin_amdgcn_readlane(__float_as_uint(cp.z), c));
            float cs = __uint_as_float(__builtin_amdgcn_readlane(__float_as_uint(cp.w), c));
            float dot = __builtin_fmaf(cz, qz, __builtin_fmaf(cy, qy, __fmul_rn(cx, qx)));
            float d = __fsub_rn(__fadd_rn(qs, cs), __fmul_rn(2.0f, dot));
            if (d < thr) mask |= (1ull << c);
        }
        while (mask) {
            int c = __builtin_ctzll(mask);
            mask &= mask - 1;
            float4 p2 = pts[base + c];
            float dot = __builtin_fmaf(p2.z, qz, __builtin_fmaf(p2.y, qy, __fmul_rn(p2.x, qx)));
            float d = __fsub_rn(__fadd_rn(qs, p2.w), __fmul_rn(2.0f, dot));
            if (d < thr) {
                u32 ub = __float_as_uint(d);
                u32 e = (ub & 0x80000000u) ? ~ub : (ub | 0x80000000u);
                u64 key = (((u64)e) << 32) | (u32)(base + c);
#pragma unroll
                for (int k = 0; k < KNN; ++k) {
                    u64 lo = key < list[k] ? key : list[k];
                    u64 hi = key < list[k] ? list[k] : key;
                    list[k] = lo; key = hi;
                }
                u32 e19 = (u32)(list[KNN - 1] >> 32);
                u32 ud = (e19 & 0x80000000u) ? (e19 & 0x7FFFFFFFu) : ~e19;
                thr = __uint_as_float(ud);
            }
        }
    }
    u16* out = nbr + (u64)(cloud * PCLD + qi) * KNN;
#pragma unroll
    for (int k = 0; k < KNN; ++k) out[k] = (u16)(u32)list[k];
}

// ---------------------------------------------------------------------------
// Transfer MLP: h0 = encode(bf16(x @ Wt + bt)) in sliced layout.
// 16 threads per point, 8 channels each.
// ---------------------------------------------------------------------------
__global__ __launch_bounds__(256) void feat_kernel(const float* __restrict__ x,
                                                   const float* __restrict__ Wt,
                                                   const float* __restrict__ bt,
                                                   u16* __restrict__ h0e) {
    int gid = blockIdx.x * 256 + threadIdx.x;   // NPTS*16
    int i = gid >> 4;
    int g = gid & 15;            // slice id == 8-channel group
    int c0 = g << 3;
    float x0 = x[3 * i], x1 = x[3 * i + 1], x2 = x[3 * i + 2];
    u32 o[4];
#pragma unroll
    for (int j = 0; j < 8; j += 2) {
        int c = c0 + j;
        float a0 = bt[c]     + x0 * Wt[c]     + x1 * Wt[128 + c]     + x2 * Wt[256 + c];
        float a1 = bt[c + 1] + x0 * Wt[c + 1] + x1 * Wt[128 + c + 1] + x2 * Wt[256 + c + 1];
        o[j >> 1] = enc2(((u32)f2bf(a0)) | (((u32)f2bf(a1)) << 16));
    }
    uint4* dst = (uint4*)&h0e[(u64)g * NPTS * 8 + (u64)i * 8];
    *dst = make_uint4(o[0], o[1], o[2], o[3]);
}

// ---------------------------------------------------------------------------
// Aggregation: per (cloud, slice) block. Stage cloud's encoded slice
// (2048 x 16 B) in LDS coalesced; gather-max = ds_read_b64 + v_pk_max_u16.
// Output agg (still encoded) in sliced layout, fully coalesced.
// ---------------------------------------------------------------------------
__global__ __launch_bounds__(256) void agg_kernel(const u16* __restrict__ he,
                                                  const u16* __restrict__ nbr,
                                                  u16* __restrict__ agge) {
    __shared__ u16 hL[PCLD * 12];   // 24 B/row: 16 B data + 8 B pad (bank spread)
    const int tid = threadIdx.x;
    const int cloud = blockIdx.x >> 4;       // 32 clouds x 16 slices
    const int s = blockIdx.x & 15;
    const u16* __restrict__ src = he + (u64)s * NPTS * 8 + (u64)cloud * PCLD * 8;

    // stage: rows tid+256k, one uint4 per row (coalesced), 2x ds_write_b64
    for (int k = 0; k < 8; ++k) {
        int r = tid + 256 * k;
        const u64* sp = (const u64*)&src[(u64)r * 8];
        u64 a = sp[0], b = sp[1];
        u64* dp = (u64*)&hL[r * 12];
        dp[0] = a; dp[1] = b;
    }
    __syncthreads();

    const int rowbase = cloud * PCLD;
    for (int k = 0; k < 8; ++k) {
        int r = tid + 256 * k;
        const u64* sp = (const u64*)&hL[r * 12];
        u64 s0 = sp[0], s1 = sp[1];
        u32 m0 = (u32)s0, m1 = (u32)(s0 >> 32), m2 = (u32)s1, m3 = (u32)(s1 >> 32);
        const u64* nb8 = (const u64*)(nbr + (u64)(rowbase + r) * KNN);
        u64 nq[5];
#pragma unroll
        for (int w = 0; w < 5; ++w) nq[w] = nb8[w];
#pragma unroll
        for (int t = 0; t < KNN; ++t) {
            int loc = (int)(nq[t >> 2] >> ((t & 3) * 16)) & (PCLD - 1);
            const u64* np = (const u64*)&hL[loc * 12];
            u64 a = np[0], b = np[1];
            m0 = max2(m0, (u32)a); m1 = max2(m1, (u32)(a >> 32));
            m2 = max2(m2, (u32)b); m3 = max2(m3, (u32)(b >> 32));
        }
        uint4* dst = (uint4*)&agge[(u64)s * NPTS * 8 + (u64)(rowbase + r) * 8];
        *dst = make_uint4(m0, m1, m2, m3);   // coalesced (lanes = consecutive rows)
    }
}

// ---------------------------------------------------------------------------
// GEMM layer: load agg (decode) -> GEMM1(128->256)+ReLU -> GEMM2(256->128)
// -> bias + BN(+ReLU) -> out (encoded sliced u16, or fp32 dense final).
// Block = 256 thr (4 waves), 64 rows.
// ---------------------------------------------------------------------------
template <int RELU_OUT, int OUT_F32>
__global__ __launch_bounds__(256) void gemm_kernel(
    const u16* __restrict__ agge,
    const u16* __restrict__ W1T, const float* __restrict__ b1,
    const u16* __restrict__ W2T, const float* __restrict__ b2,
    const float* __restrict__ g, const float* __restrict__ be,
    const float* __restrict__ rm, const float* __restrict__ rv,
    void* __restrict__ hout_v) {
    __shared__ u16 aggL[64][136];   // +8 pad
    __shared__ u16 hidL[64][264];   // +8 pad
    const int tid = threadIdx.x;
    const int R = blockIdx.x * 64;

    // ---- Phase A': coalesced load of agg rows + decode -> LDS
    {
        const int r = tid >> 2, cg = tid & 3;   // 64 rows x 4 groups of 32 ch
        const int gr = R + r;
#pragma unroll
        for (int h = 0; h < 4; ++h) {
            const int s = 4 * cg + h;
            const u32* src = (const u32*)(agge + (u64)s * NPTS * 8 + (u64)gr * 8);
            u32 w0 = src[0], w1 = src[1], w2 = src[2], w3 = src[3];
            u32* dst = (u32*)&aggL[r][cg * 32 + h * 8];
            dst[0] = dec2(w0); dst[1] = dec2(w1); dst[2] = dec2(w2); dst[3] = dec2(w3);
        }
    }
    __syncthreads();

    const int wv = tid >> 6, lane = tid & 63;
    const int lr = lane & 15;
    const int lq = lane >> 4;

    // ---- Phase B: hid = relu(agg @ W1 + b1) -> hidL  (wave owns 64 n-cols)
    {
        f32x4 acc[4][4];
#pragma unroll
        for (int i = 0; i < 4; ++i)
#pragma unroll
            for (int j = 0; j < 4; ++j) acc[i][j] = (f32x4)(0.0f);
        const int nb0 = wv * 64;
#pragma unroll
        for (int ks = 0; ks < 4; ++ks) {
            const int kcol = ks * 32 + lq * 8;
            bf16x8 af[4], bfr[4];
#pragma unroll
            for (int mt = 0; mt < 4; ++mt)
                af[mt] = *(const bf16x8*)&aggL[mt * 16 + lr][kcol];
#pragma unroll
            for (int nt = 0; nt < 4; ++nt)
                bfr[nt] = *(const bf16x8*)&W1T[(u64)(nb0 + nt * 16 + lr) * HD + kcol];
#pragma unroll
            for (int mt = 0; mt < 4; ++mt)
#pragma unroll
                for (int nt = 0; nt < 4; ++nt)
                    acc[mt][nt] = __builtin_amdgcn_mfma_f32_16x16x32_bf16(af[mt], bfr[nt], acc[mt][nt], 0, 0, 0);
        }
#pragma unroll
        for (int nt = 0; nt < 4; ++nt) {
            const int c = nb0 + nt * 16 + lr;
            const float bias = b1[c];
#pragma unroll
            for (int mt = 0; mt < 4; ++mt)
#pragma unroll
                for (int r2 = 0; r2 < 4; ++r2) {
                    float v = fmaxf(acc[mt][nt][r2] + bias, 0.0f);
                    hidL[mt * 16 + lq * 4 + r2][c] = f2bf(v);
                }
        }
    }
    __syncthreads();

    // ---- Phase C: out = BN(hid @ W2 + b2) (+ReLU) -> global
    {
        f32x4 acc[4][2];
#pragma unroll
        for (int i = 0; i < 4; ++i) { acc[i][0] = (f32x4)(0.0f); acc[i][1] = (f32x4)(0.0f); }
        const int nb0 = wv * 32;
#pragma unroll
        for (int ks = 0; ks < 8; ++ks) {
            const int kcol = ks * 32 + lq * 8;
            bf16x8 af[4], bfr[2];
#pragma unroll
            for (int mt = 0; mt < 4; ++mt)
                af[mt] = *(const bf16x8*)&hidL[mt * 16 + lr][kcol];
#pragma unroll
            for (int nt = 0; nt < 2; ++nt)
                bfr[nt] = *(const bf16x8*)&W2T[(u64)(nb0 + nt * 16 + lr) * HD2 + kcol];
#pragma unroll
            for (int mt = 0; mt < 4; ++mt)
#pragma unroll
                for (int nt = 0; nt < 2; ++nt)
                    acc[mt][nt] = __builtin_amdgcn_mfma_f32_16x16x32_bf16(af[mt], bfr[nt], acc[mt][nt], 0, 0, 0);
        }
#pragma unroll
        for (int nt = 0; nt < 2; ++nt) {
            const int c = nb0 + nt * 16 + lr;
            const float bias = b2[c];
            const float sc = g[c] * (1.0f / sqrtf(rv[c] + 1e-5f));
            const float rmc = rm[c];
            const float bec = be[c];
#pragma unroll
            for (int mt = 0; mt < 4; ++mt)
#pragma unroll
                for (int r2 = 0; r2 < 4; ++r2) {
                    float v = acc[mt][nt][r2] + bias;
                    v = (v - rmc) * sc + bec;
                    if (RELU_OUT) v = fmaxf(v, 0.0f);
                    const int row = R + mt * 16 + lq * 4 + r2;
                    if (OUT_F32) {
                        ((float*)hout_v)[(u64)row * HD + c] = v;
                    } else {
                        u16 b = f2bf(v);
                        u16 e = b ^ ((b & 0x8000u) ? (u16)0xFFFFu : (u16)0x8000u);
                        ((u16*)hout_v)[(u64)(c >> 3) * NPTS * 8 + (u64)row * 8 + (c & 7)] = e;
                    }
                }
        }
    }
}

// ---------------------------------------------------------------------------
extern "C" void kernel_launch(void* const* d_in, const int* in_sizes, int n_in,
                              void* d_out, int out_size, void* d_ws, size_t ws_size,
                              hipStream_t stream) {
    const float* x    = (const float*)d_in[0];
    const float* Wt   = (const float*)d_in[2];
    const float* bt   = (const float*)d_in[3];
    const float* W1_0 = (const float*)d_in[4];
    const float* b1_0 = (const float*)d_in[5];
    const float* W2_0 = (const float*)d_in[6];
    const float* b2_0 = (const float*)d_in[7];
    const float* g0   = (const float*)d_in[8];
    const float* be0  = (const float*)d_in[9];
    const float* rm0  = (const float*)d_in[10];
    const float* rv0  = (const float*)d_in[11];
    const float* W1_1 = (const float*)d_in[12];
    const float* b1_1 = (const float*)d_in[13];
    const float* W2_1 = (const float*)d_in[14];
    const float* b2_1 = (const float*)d_in[15];
    const float* g1   = (const float*)d_in[16];
    const float* be1  = (const float*)d_in[17];
    const float* rm1  = (const float*)d_in[18];
    const float* rv1  = (const float*)d_in[19];

    char* ws = (char*)d_ws;
    u16* he   = (u16*)ws;                                   // 16 MB: h0e, later h1e
    u16* agge = (u16*)(ws + 16777216);                      // 16 MB
    u16* W10T = (u16*)(ws + 2 * 16777216);                  // 64 KB each
    u16* W20T = W10T + 32768;
    u16* W11T = W20T + 32768;
    u16* W21T = W11T + 32768;
    u16* nbr  = (u16*)(ws + 2 * 16777216 + 4 * 65536);      // 2.62 MB
    // total ws ~35.2 MB

    knn_kernel<<<256, 256, 0, stream>>>(x, nbr);
    prep_kernel<<<512, 256, 0, stream>>>(W1_0, W2_0, W1_1, W2_1, W10T, W20T, W11T, W21T);
    feat_kernel<<<4096, 256, 0, stream>>>(x, Wt, bt, he);
    // layer 0
    agg_kernel<<<512, 256, 0, stream>>>(he, nbr, agge);
    gemm_kernel<1, 0><<<1024, 256, 0, stream>>>(agge, W10T, b1_0, W20T, b2_0,
                                                g0, be0, rm0, rv0, he);   // he := h1e
    // layer 1
    agg_kernel<<<512, 256, 0, stream>>>(he, nbr, agge);
    gemm_kernel<0, 1><<<1024, 256, 0, stream>>>(agge, W11T, b1_1, W21T, b2_1,
                                                g1, be1, rm1, rv1, d_out);
}

// Round 9
// 343.087 us; speedup vs baseline: 1.0322x; 1.0322x over previous
//
#include <hip/hip_runtime.h>

typedef unsigned int u32;
typedef unsigned short u16;
typedef unsigned long long u64;

// Problem constants
#define NPTS 65536
#define PCLD 2048
#define KNN 20
#define HD 128
#define HD2 256
// activations at rest: 16 slices of 8 channels, ORDER-ENCODED u16
// layout: he[slice][row][8]  (16 B per row per slice)

typedef __attribute__((ext_vector_type(8))) short bf16x8;   // 8 bf16 (4 VGPRs)
typedef __attribute__((ext_vector_type(4))) float f32x4;    // C/D frag
typedef unsigned short us2 __attribute__((ext_vector_type(2)));

__device__ __forceinline__ u16 f2bf(float f) {
    u32 u = __float_as_uint(f);
    u32 r = (u + 0x7FFFu + ((u >> 16) & 1u)) >> 16;  // RNE
    return (u16)r;
}
// order-encode: bf16 bits -> monotone u16 (unsigned compare == float compare)
__device__ __forceinline__ u32 enc2(u32 b) {             // 2 packed values
    u32 s = (b >> 15) & 0x00010001u;
    return b ^ (s * 0x7FFFu) ^ 0x80008000u;
}
__device__ __forceinline__ u32 dec2(u32 e) {
    u32 s = ((~e) >> 15) & 0x00010001u;
    return e ^ (s * 0x7FFFu) ^ 0x80008000u;
}
__device__ __forceinline__ u32 max2(u32 a, u32 b) {      // per-u16 unsigned max
#if __has_builtin(__builtin_elementwise_max)
    us2 x, y; __builtin_memcpy(&x, &a, 4); __builtin_memcpy(&y, &b, 4);
    us2 r = __builtin_elementwise_max(x, y);
    u32 o; __builtin_memcpy(&o, &r, 4); return o;
#else
    u32 lo = ((a & 0xFFFFu) > (b & 0xFFFFu)) ? (a & 0xFFFFu) : (b & 0xFFFFu);
    u32 hi = ((a >> 16) > (b >> 16)) ? (a & 0xFFFF0000u) : (b & 0xFFFF0000u);
    return lo | hi;
#endif
}

// ---------------------------------------------------------------------------
// Weight prep: fp32 -> bf16 + transpose (unchanged).
// ---------------------------------------------------------------------------
__global__ __launch_bounds__(256) void prep_kernel(
    const float* __restrict__ W1_0, const float* __restrict__ W2_0,
    const float* __restrict__ W1_1, const float* __restrict__ W2_1,
    u16* __restrict__ W1_0T, u16* __restrict__ W2_0T,
    u16* __restrict__ W1_1T, u16* __restrict__ W2_1T) {
    int id = blockIdx.x * 256 + threadIdx.x;   // 4 * 32768 threads
    int m = id >> 15, e = id & 32767;
    if (m == 0)      { int n = e >> 7, k = e & 127; W1_0T[e] = f2bf(W1_0[k * 256 + n]); }
    else if (m == 1) { int n = e >> 8, k = e & 255; W2_0T[e] = f2bf(W2_0[k * 128 + n]); }
    else if (m == 2) { int n = e >> 7, k = e & 127; W1_1T[e] = f2bf(W1_1[k * 256 + n]); }
    else             { int n = e >> 8, k = e & 255; W2_1T[e] = f2bf(W2_1[k * 128 + n]); }
}

// ---------------------------------------------------------------------------
// kNN — EXACT R2 structure (empirical best: 155 us; DO NOT MODIFY).
// readlane broadcast beat uniform-LDS (202), uniform-VMEM (204), SMEM (1200).
// ---------------------------------------------------------------------------
__global__ __launch_bounds__(256) void knn_kernel(const float* __restrict__ x,
                                                  u16* __restrict__ nbr) {
    __shared__ float4 pts[PCLD];
    const int cloud = blockIdx.x >> 3;
    const int qi = ((blockIdx.x & 7) << 8) + threadIdx.x;   // local query idx
    const float* xc = x + (u64)cloud * PCLD * 3;
    for (int t = threadIdx.x; t < PCLD; t += 256) {
        float a = xc[3 * t], b = xc[3 * t + 1], c = xc[3 * t + 2];
        float sq = __fadd_rn(__fadd_rn(__fmul_rn(a, a), __fmul_rn(b, b)), __fmul_rn(c, c));
        pts[t] = make_float4(a, b, c, sq);
    }
    __syncthreads();
    const float4 q = pts[qi];
    const float qx = q.x, qy = q.y, qz = q.z, qs = q.w;
    const int lane = threadIdx.x & 63;
    u64 list[KNN];
#pragma unroll
    for (int k = 0; k < KNN; ++k) list[k] = 0xFF800000FFFFFFFFull;  // enc(+inf)
    float thr = __builtin_inff();

    for (int base = 0; base < PCLD; base += 64) {
        float4 cp = pts[base + lane];   // 1 ds_read_b128 per 64 candidates
        u64 mask = 0;
#pragma unroll
        for (int c = 0; c < 64; ++c) {
            float cx = __uint_as_float(__builtin_amdgcn_readlane(__float_as_uint(cp.x), c));
            float cy = __uint_as_float(__builtin_amdgcn_readlane(__float_as_uint(cp.y), c));
            float cz = __uint_as_float(__builtin_amdgcn_readlane(__float_as_uint(cp.z), c));
            float cs = __uint_as_float(__builtin_amdgcn_readlane(__float_as_uint(cp.w), c));
            float dot = __builtin_fmaf(cz, qz, __builtin_fmaf(cy, qy, __fmul_rn(cx, qx)));
            float d = __fsub_rn(__fadd_rn(qs, cs), __fmul_rn(2.0f, dot));
            if (d < thr) mask |= (1ull << c);
        }
        while (mask) {
            int c = __builtin_ctzll(mask);
            mask &= mask - 1;
            float4 p2 = pts[base + c];
            float dot = __builtin_fmaf(p2.z, qz, __builtin_fmaf(p2.y, qy, __fmul_rn(p2.x, qx)));
            float d = __fsub_rn(__fadd_rn(qs, p2.w), __fmul_rn(2.0f, dot));
            if (d < thr) {
                u32 ub = __float_as_uint(d);
                u32 e = (ub & 0x80000000u) ? ~ub : (ub | 0x80000000u);
                u64 key = (((u64)e) << 32) | (u32)(base + c);
#pragma unroll
                for (int k = 0; k < KNN; ++k) {
                    u64 lo = key < list[k] ? key : list[k];
                    u64 hi = key < list[k] ? list[k] : key;
                    list[k] = lo; key = hi;
                }
                u32 e19 = (u32)(list[KNN - 1] >> 32);
                u32 ud = (e19 & 0x80000000u) ? (e19 & 0x7FFFFFFFu) : ~e19;
                thr = __uint_as_float(ud);
            }
        }
    }
    u16* out = nbr + (u64)(cloud * PCLD + qi) * KNN;
#pragma unroll
    for (int k = 0; k < KNN; ++k) out[k] = (u16)(u32)list[k];
}

// ---------------------------------------------------------------------------
// Transfer MLP: h0 = encode(bf16(x @ Wt + bt)) in sliced layout.
// ---------------------------------------------------------------------------
__global__ __launch_bounds__(256) void feat_kernel(const float* __restrict__ x,
                                                   const float* __restrict__ Wt,
                                                   const float* __restrict__ bt,
                                                   u16* __restrict__ h0e) {
    int gid = blockIdx.x * 256 + threadIdx.x;   // NPTS*16
    int i = gid >> 4;
    int g = gid & 15;            // slice id == 8-channel group
    int c0 = g << 3;
    float x0 = x[3 * i], x1 = x[3 * i + 1], x2 = x[3 * i + 2];
    u32 o[4];
#pragma unroll
    for (int j = 0; j < 8; j += 2) {
        int c = c0 + j;
        float a0 = bt[c]     + x0 * Wt[c]     + x1 * Wt[128 + c]     + x2 * Wt[256 + c];
        float a1 = bt[c + 1] + x0 * Wt[c + 1] + x1 * Wt[128 + c + 1] + x2 * Wt[256 + c + 1];
        o[j >> 1] = enc2(((u32)f2bf(a0)) | (((u32)f2bf(a1)) << 16));
    }
    uint4* dst = (uint4*)&h0e[(u64)g * NPTS * 8 + (u64)i * 8];
    *dst = make_uint4(o[0], o[1], o[2], o[3]);
}

// ---------------------------------------------------------------------------
// Aggregation v2: per (cloud, slice) block. Rows at NATURAL 16 B stride
// (32 KB exactly): gather = ONE ds_read_b128 per neighbor row. b128 random
// rows at 4-dword stride hit the b128 bank floor (~8/bank) -- R8's 24 B
// stride (gcd(6,32)=2 -> even banks only, 4-way conflict) was the bug.
// ---------------------------------------------------------------------------
__global__ __launch_bounds__(256) void agg_kernel(const u16* __restrict__ he,
                                                  const u16* __restrict__ nbr,
                                                  u16* __restrict__ agge) {
    __shared__ u16 hL[PCLD * 8];   // 32 KB, 16 B per row, b128-aligned
    const int tid = threadIdx.x;
    const int cloud = blockIdx.x >> 4;       // 32 clouds x 16 slices
    const int s = blockIdx.x & 15;
    const u16* __restrict__ src = he + (u64)s * NPTS * 8 + (u64)cloud * PCLD * 8;

    // stage: rows tid+256k, one uint4 global read + one b128 LDS write (coalesced)
    for (int k = 0; k < 8; ++k) {
        int r = tid + 256 * k;
        *(uint4*)&hL[r * 8] = *(const uint4*)&src[(u64)r * 8];
    }
    __syncthreads();

    const int rowbase = cloud * PCLD;
    for (int k = 0; k < 8; ++k) {
        int r = tid + 256 * k;
        uint4 m = *(const uint4*)&hL[r * 8];
        const u64* nb8 = (const u64*)(nbr + (u64)(rowbase + r) * KNN);
        u64 nq[5];
#pragma unroll
        for (int w = 0; w < 5; ++w) nq[w] = nb8[w];
#pragma unroll
        for (int t = 0; t < KNN; ++t) {
            int loc = (int)(nq[t >> 2] >> ((t & 3) * 16)) & (PCLD - 1);
            uint4 v = *(const uint4*)&hL[loc * 8];   // single ds_read_b128
            m.x = max2(m.x, v.x); m.y = max2(m.y, v.y);
            m.z = max2(m.z, v.z); m.w = max2(m.w, v.w);
        }
        *(uint4*)&agge[(u64)s * NPTS * 8 + (u64)(rowbase + r) * 8] = m;  // coalesced
    }
}

// ---------------------------------------------------------------------------
// GEMM layer: load agg (decode) -> GEMM1(128->256)+ReLU -> GEMM2(256->128)
// -> bias + BN(+ReLU) -> out (encoded sliced u16, or fp32 dense final).
// Block = 256 thr (4 waves), 64 rows. (unchanged from R8)
// ---------------------------------------------------------------------------
template <int RELU_OUT, int OUT_F32>
__global__ __launch_bounds__(256) void gemm_kernel(
    const u16* __restrict__ agge,
    const u16* __restrict__ W1T, const float* __restrict__ b1,
    const u16* __restrict__ W2T, const float* __restrict__ b2,
    const float* __restrict__ g, const float* __restrict__ be,
    const float* __restrict__ rm, const float* __restrict__ rv,
    void* __restrict__ hout_v) {
    __shared__ u16 aggL[64][136];   // +8 pad
    __shared__ u16 hidL[64][264];   // +8 pad
    const int tid = threadIdx.x;
    const int R = blockIdx.x * 64;

    // ---- Phase A': coalesced load of agg rows + decode -> LDS
    {
        const int r = tid >> 2, cg = tid & 3;   // 64 rows x 4 groups of 32 ch
        const int gr = R + r;
#pragma unroll
        for (int h = 0; h < 4; ++h) {
            const int s = 4 * cg + h;
            const u32* src = (const u32*)(agge + (u64)s * NPTS * 8 + (u64)gr * 8);
            u32 w0 = src[0], w1 = src[1], w2 = src[2], w3 = src[3];
            u32* dst = (u32*)&aggL[r][cg * 32 + h * 8];
            dst[0] = dec2(w0); dst[1] = dec2(w1); dst[2] = dec2(w2); dst[3] = dec2(w3);
        }
    }
    __syncthreads();

    const int wv = tid >> 6, lane = tid & 63;
    const int lr = lane & 15;
    const int lq = lane >> 4;

    // ---- Phase B: hid = relu(agg @ W1 + b1) -> hidL  (wave owns 64 n-cols)
    {
        f32x4 acc[4][4];
#pragma unroll
        for (int i = 0; i < 4; ++i)
#pragma unroll
            for (int j = 0; j < 4; ++j) acc[i][j] = (f32x4)(0.0f);
        const int nb0 = wv * 64;
#pragma unroll
        for (int ks = 0; ks < 4; ++ks) {
            const int kcol = ks * 32 + lq * 8;
            bf16x8 af[4], bfr[4];
#pragma unroll
            for (int mt = 0; mt < 4; ++mt)
                af[mt] = *(const bf16x8*)&aggL[mt * 16 + lr][kcol];
#pragma unroll
            for (int nt = 0; nt < 4; ++nt)
                bfr[nt] = *(const bf16x8*)&W1T[(u64)(nb0 + nt * 16 + lr) * HD + kcol];
#pragma unroll
            for (int mt = 0; mt < 4; ++mt)
#pragma unroll
                for (int nt = 0; nt < 4; ++nt)
                    acc[mt][nt] = __builtin_amdgcn_mfma_f32_16x16x32_bf16(af[mt], bfr[nt], acc[mt][nt], 0, 0, 0);
        }
#pragma unroll
        for (int nt = 0; nt < 4; ++nt) {
            const int c = nb0 + nt * 16 + lr;
            const float bias = b1[c];
#pragma unroll
            for (int mt = 0; mt < 4; ++mt)
#pragma unroll
                for (int r2 = 0; r2 < 4; ++r2) {
                    float v = fmaxf(acc[mt][nt][r2] + bias, 0.0f);
                    hidL[mt * 16 + lq * 4 + r2][c] = f2bf(v);
                }
        }
    }
    __syncthreads();

    // ---- Phase C: out = BN(hid @ W2 + b2) (+ReLU) -> global
    {
        f32x4 acc[4][2];
#pragma unroll
        for (int i = 0; i < 4; ++i) { acc[i][0] = (f32x4)(0.0f); acc[i][1] = (f32x4)(0.0f); }
        const int nb0 = wv * 32;
#pragma unroll
        for (int ks = 0; ks < 8; ++ks) {
            const int kcol = ks * 32 + lq * 8;
            bf16x8 af[4], bfr[2];
#pragma unroll
            for (int mt = 0; mt < 4; ++mt)
                af[mt] = *(const bf16x8*)&hidL[mt * 16 + lr][kcol];
#pragma unroll
            for (int nt = 0; nt < 2; ++nt)
                bfr[nt] = *(const bf16x8*)&W2T[(u64)(nb0 + nt * 16 + lr) * HD2 + kcol];
#pragma unroll
            for (int mt = 0; mt < 4; ++mt)
#pragma unroll
                for (int nt = 0; nt < 2; ++nt)
                    acc[mt][nt] = __builtin_amdgcn_mfma_f32_16x16x32_bf16(af[mt], bfr[nt], acc[mt][nt], 0, 0, 0);
        }
#pragma unroll
        for (int nt = 0; nt < 2; ++nt) {
            const int c = nb0 + nt * 16 + lr;
            const float bias = b2[c];
            const float sc = g[c] * (1.0f / sqrtf(rv[c] + 1e-5f));
            const float rmc = rm[c];
            const float bec = be[c];
#pragma unroll
            for (int mt = 0; mt < 4; ++mt)
#pragma unroll
                for (int r2 = 0; r2 < 4; ++r2) {
                    float v = acc[mt][nt][r2] + bias;
                    v = (v - rmc) * sc + bec;
                    if (RELU_OUT) v = fmaxf(v, 0.0f);
                    const int row = R + mt * 16 + lq * 4 + r2;
                    if (OUT_F32) {
                        ((float*)hout_v)[(u64)row * HD + c] = v;
                    } else {
                        u16 b = f2bf(v);
                        u16 e = b ^ ((b & 0x8000u) ? (u16)0xFFFFu : (u16)0x8000u);
                        ((u16*)hout_v)[(u64)(c >> 3) * NPTS * 8 + (u64)row * 8 + (c & 7)] = e;
                    }
                }
        }
    }
}

// ---------------------------------------------------------------------------
extern "C" void kernel_launch(void* const* d_in, const int* in_sizes, int n_in,
                              void* d_out, int out_size, void* d_ws, size_t ws_size,
                              hipStream_t stream) {
    const float* x    = (const float*)d_in[0];
    const float* Wt   = (const float*)d_in[2];
    const float* bt   = (const float*)d_in[3];
    const float* W1_0 = (const float*)d_in[4];
    const float* b1_0 = (const float*)d_in[5];
    const float* W2_0 = (const float*)d_in[6];
    const float* b2_0 = (const float*)d_in[7];
    const float* g0   = (const float*)d_in[8];
    const float* be0  = (const float*)d_in[9];
    const float* rm0  = (const float*)d_in[10];
    const float* rv0  = (const float*)d_in[11];
    const float* W1_1 = (const float*)d_in[12];
    const float* b1_1 = (const float*)d_in[13];
    const float* W2_1 = (const float*)d_in[14];
    const float* b2_1 = (const float*)d_in[15];
    const float* g1   = (const float*)d_in[16];
    const float* be1  = (const float*)d_in[17];
    const float* rm1  = (const float*)d_in[18];
    const float* rv1  = (const float*)d_in[19];

    char* ws = (char*)d_ws;
    u16* he   = (u16*)ws;                                   // 16 MB: h0e, later h1e
    u16* agge = (u16*)(ws + 16777216);                      // 16 MB
    u16* W10T = (u16*)(ws + 2 * 16777216);                  // 64 KB each
    u16* W20T = W10T + 32768;
    u16* W11T = W20T + 32768;
    u16* W21T = W11T + 32768;
    u16* nbr  = (u16*)(ws + 2 * 16777216 + 4 * 65536);      // 2.62 MB
    // total ws ~35.2 MB

    knn_kernel<<<256, 256, 0, stream>>>(x, nbr);
    prep_kernel<<<512, 256, 0, stream>>>(W1_0, W2_0, W1_1, W2_1, W10T, W20T, W11T, W21T);
    feat_kernel<<<4096, 256, 0, stream>>>(x, Wt, bt, he);
    // layer 0
    agg_kernel<<<512, 256, 0, stream>>>(he, nbr, agge);
    gemm_kernel<1, 0><<<1024, 256, 0, stream>>>(agge, W10T, b1_0, W20T, b2_0,
                                                g0, be0, rm0, rv0, he);   // he := h1e
    // layer 1
    agg_kernel<<<512, 256, 0, stream>>>(he, nbr, agge);
    gemm_kernel<0, 1><<<1024, 256, 0, stream>>>(agge, W11T, b1_1, W21T, b2_1,
                                                g1, be1, rm1, rv1, d_out);
}